// Round 6
// baseline (388.227 us; speedup 1.0000x reference)
//
#include <hip/hip_runtime.h>
#include <hip/hip_bf16.h>

#define LL 512
#define DD 1024
#define HH 8
#define DKK 128
#define QQ 256
#define CCC 128
#define TTT 128
#define RR 50
#define FFF 4096

typedef __attribute__((ext_vector_type(8))) short short8;
typedef __attribute__((ext_vector_type(4))) float float4v;

__device__ __forceinline__ unsigned short f2bu(float f) {
  __hip_bfloat16 h = __float2bfloat16(f);
  unsigned short u; __builtin_memcpy(&u, &h, 2); return u;
}
__device__ __forceinline__ float b2f(unsigned short u) {
  unsigned int v = ((unsigned int)u) << 16;
  float f; __builtin_memcpy(&f, &v, 4); return f;
}

// barrier that only drains LDS (lgkmcnt(0)); global loads stay in flight.
// 0xC07F = vmcnt(63) expcnt(7) lgkmcnt(0) on gfx9-family encoding.
__device__ __forceinline__ void lds_barrier() {
  __builtin_amdgcn_sched_barrier(0);
  __builtin_amdgcn_s_waitcnt(0xC07F);
  __builtin_amdgcn_s_barrier();
  __builtin_amdgcn_sched_barrier(0);
}

// ---------------- weight fp32->bf16 conversion ----------------
__global__ __launch_bounds__(256) void conv_kernel(
    const float* __restrict__ Wq, const float* __restrict__ Wk,
    const float* __restrict__ Wv, const float* __restrict__ Wo,
    const float* __restrict__ W1, const float* __restrict__ W2,
    const float* __restrict__ bq, const float* __restrict__ bk,
    const float* __restrict__ bv,
    unsigned short* __restrict__ wqkv, unsigned short* __restrict__ wo,
    unsigned short* __restrict__ w1, unsigned short* __restrict__ w2,
    float* __restrict__ bqkv)
{
  int g = blockIdx.x * 256 + threadIdx.x;   // quad (4-float) index
  const float* src; unsigned short* dst; int off;
  if (g < 262144)        { src = Wq; dst = wqkv;           off = g; }
  else if (g < 524288)   { src = Wk; dst = wqkv + 1048576; off = g - 262144; }
  else if (g < 786432)   { src = Wv; dst = wqkv + 2097152; off = g - 524288; }
  else if (g < 1048576)  { src = Wo; dst = wo;             off = g - 786432; }
  else if (g < 2097152)  { src = W1; dst = w1;             off = g - 1048576; }
  else if (g < 3145728)  { src = W2; dst = w2;             off = g - 2097152; }
  else if (g < 3145728 + 768) {
    int q = g - 3145728;
    const float* s = (q < 256) ? bq : (q < 512) ? bk : bv;
    ((float4*)bqkv)[q] = ((const float4*)s)[q & 255];
    return;
  } else return;
  float4 v = ((const float4*)src)[off];
  ushort4 o4;
  o4.x = f2bu(v.x); o4.y = f2bu(v.y); o4.z = f2bu(v.z); o4.w = f2bu(v.w);
  ((ushort4*)dst)[off] = o4;
}

// ---------------- LayerNorm: fp32 in, bf16 out ----------------
__global__ __launch_bounds__(256) void ln_bf16_kernel(const float* __restrict__ x,
    const float* __restrict__ g, const float* __restrict__ b,
    unsigned short* __restrict__ y)
{
  int row = blockIdx.x, t = threadIdx.x;
  const float4 xv = ((const float4*)(x + row*DD))[t];
  float s  = xv.x+xv.y+xv.z+xv.w;
  float ss = xv.x*xv.x+xv.y*xv.y+xv.z*xv.z+xv.w*xv.w;
  __shared__ float rs[256], rss[256];
  rs[t]=s; rss[t]=ss; __syncthreads();
  for (int st=128; st>0; st>>=1){ if (t<st){ rs[t]+=rs[t+st]; rss[t]+=rss[t+st]; } __syncthreads(); }
  float mean = rs[0] * (1.0f/DD);
  float var  = rss[0]*(1.0f/DD) - mean*mean;
  float inv  = rsqrtf(var + 1e-5f);
  float4 gv = ((const float4*)g)[t], bv = ((const float4*)b)[t];
  ushort4 ov;
  ov.x = f2bu((xv.x-mean)*inv*gv.x + bv.x);
  ov.y = f2bu((xv.y-mean)*inv*gv.y + bv.y);
  ov.z = f2bu((xv.z-mean)*inv*gv.z + bv.z);
  ov.w = f2bu((xv.w-mean)*inv*gv.w + bv.w);
  ((ushort4*)(y + row*DD))[t] = ov;
}

// ---------------- tiny: out[row, col] += b2[col] ----------------
__global__ __launch_bounds__(256) void addbias_kernel(float* __restrict__ out,
                                                      const float* __restrict__ b2)
{
  int g = blockIdx.x*256 + threadIdx.x;   // over L*D
  out[g] += b2[g & (DD-1)];
}

// ======== VGPR-staged pipelined bf16 MFMA GEMM (static ping-pong) ========
// C[z][M,N] = A[z][M,K](lda) @ B[z][N,K](ldb)^T (+bias,+src,relu)
// 256 thr = 4 waves (2x2), wave tile (BM/2)x(BN/2), BK=64, nit must be even.
// Two named register sets Ra/Rb (no dynamic indexing -> no scratch spill).
// lds_barrier() drains only lgkmcnt; global-load vmcnt waits attach to the
// ds_write one full iteration later (true prefetch across the barrier).
template<int BM, int BN, int ZK, int OUT_BF16, int RELU, int HAS_SRC, int HAS_BIAS>
__global__ __launch_bounds__(256) void gemm_pl(
    const unsigned short* __restrict__ A, int lda, size_t sAz,
    const unsigned short* __restrict__ B, int ldb, size_t sBz,
    const float* __restrict__ bias,
    const float* __restrict__ src, int ldsrc, size_t sSz,
    void* __restrict__ Cv, int ldc, size_t sCz,
    int K)
{
  constexpr int WM = BM/2, WN = BN/2, FM = WM/16, FN = WN/16;
  constexpr int NA = BM/32, NB = BN/32, NT = NA+NB;
  constexpr int ABYTES = BM*128, TILE = ABYTES + BN*128;
  __shared__ char lds[2*TILE];
  int t = threadIdx.x, w = t >> 6, l = t & 63;
  size_t z = blockIdx.z;
  const unsigned short* Az = A + z*sAz;
  const unsigned short* Bz = B + z*sBz;
  int bm = blockIdx.y*BM, bn = blockIdx.x*BN;
  int wm = (w>>1)*WM, wn = (w&1)*WN;

  float4v acc[FM][FN];
  #pragma unroll
  for (int m=0;m<FM;++m)
    #pragma unroll
    for (int n=0;n<FN;++n) acc[m][n] = (float4v){0.f,0.f,0.f,0.f};

  int r = t >> 3, sl = t & 7;
  int gc = sl ^ (r & 7);            // global chunk loaded into LDS slot sl
  int quad = l >> 4, lrow = l & 15;
  const int nit = K >> 6;           // must be even

  int4 Ra[NT], Rb[NT];

  auto load = [&](int it, int4* Rr) {
    int k0 = it << 6;
    #pragma unroll
    for (int p=0;p<NA;++p)
      Rr[p] = *(const int4*)(Az + (size_t)(bm + p*32 + r)*lda + k0 + gc*8);
    #pragma unroll
    for (int p=0;p<NB;++p)
      Rr[NA+p] = *(const int4*)(Bz + (size_t)(bn + p*32 + r)*ldb + k0 + gc*8);
  };
  auto storeLds = [&](char* base, const int4* Rr) {
    #pragma unroll
    for (int p=0;p<NA;++p)
      *(int4*)(base + (p*32 + r)*128 + sl*16) = Rr[p];
    #pragma unroll
    for (int p=0;p<NB;++p)
      *(int4*)(base + ABYTES + (p*32 + r)*128 + sl*16) = Rr[NA+p];
  };
  auto compute = [&](const char* base) {
    const char* ab = base;
    const char* bb = base + ABYTES;
    #pragma unroll
    for (int step=0; step<2; ++step) {
      int c = step*4 + quad;
      short8 af[FM], bf[FN];
      #pragma unroll
      for (int m=0;m<FM;++m) {
        int Rw = wm + m*16 + lrow;
        af[m] = *(const short8*)(ab + Rw*128 + ((c ^ (Rw & 7))*16));
      }
      #pragma unroll
      for (int n=0;n<FN;++n) {
        int Rw = wn + n*16 + lrow;
        bf[n] = *(const short8*)(bb + Rw*128 + ((c ^ (Rw & 7))*16));
      }
      #pragma unroll
      for (int m=0;m<FM;++m)
        #pragma unroll
        for (int n=0;n<FN;++n)
          acc[m][n] = __builtin_amdgcn_mfma_f32_16x16x32_bf16(af[m], bf[n], acc[m][n], 0, 0, 0);
    }
  };

  load(0, Ra);
  load(1, Rb);
  for (int it = 0; it < nit; it += 2) {
    storeLds(lds, Ra);                      // waits vmcnt for Ra only
    if (it + 2 < nit) load(it + 2, Ra);     // prefetch, stays in flight
    lds_barrier();
    compute(lds);
    storeLds(lds + TILE, Rb);
    if (it + 3 < nit) load(it + 3, Rb);
    lds_barrier();
    compute(lds + TILE);
  }

  #pragma unroll
  for (int m=0;m<FM;++m)
    #pragma unroll
    for (int n=0;n<FN;++n)
      #pragma unroll
      for (int rg=0;rg<4;++rg) {
        int row = bm + wm + m*16 + quad*4 + rg;
        int col = bn + wn + n*16 + lrow;
        float vv = acc[m][n][rg];
        if (ZK) {
          atomicAdd(&((float*)Cv)[(size_t)row*ldc + col], vv);
        } else {
          if (HAS_BIAS) vv += bias[col];
          if (HAS_SRC)  vv += src[z*sSz + (size_t)row*ldsrc + col];
          if (RELU) vv = fmaxf(vv, 0.f);
          if (OUT_BF16) ((unsigned short*)Cv)[z*sCz + (size_t)row*ldc + col] = f2bu(vv);
          else          ((float*)Cv)[z*sCz + (size_t)row*ldc + col] = vv;
        }
      }
}

// ---------------- QKV GEMM (same pipeline) + head-scatter epilogue ---------
__global__ __launch_bounds__(256) void gemm_qkv_pl(
    const unsigned short* __restrict__ A, const unsigned short* __restrict__ B,
    const float* __restrict__ bqkv,
    unsigned short* __restrict__ Qh, unsigned short* __restrict__ Kh,
    unsigned short* __restrict__ Vt)
{
  constexpr int BM = 64, BN = 64, WM = 32, WN = 32, FM = 2, FN = 2;
  constexpr int NA = 2, NB = 2, NT = 4;
  constexpr int ABYTES = BM*128, TILE = ABYTES + BN*128;
  __shared__ char lds[2*TILE];
  int t = threadIdx.x, w = t >> 6, l = t & 63;
  int bm = blockIdx.y*BM, bn = blockIdx.x*BN;
  int wm = (w>>1)*WM, wn = (w&1)*WN;
  const int K = DD, nit = K >> 6;

  float4v acc[FM][FN];
  #pragma unroll
  for (int m=0;m<FM;++m)
    #pragma unroll
    for (int n=0;n<FN;++n) acc[m][n] = (float4v){0.f,0.f,0.f,0.f};

  int r = t >> 3, sl = t & 7;
  int gc = sl ^ (r & 7);
  int quad = l >> 4, lrow = l & 15;
  int4 Ra[NT], Rb[NT];

  auto load = [&](int it, int4* Rr) {
    int k0 = it << 6;
    #pragma unroll
    for (int p=0;p<NA;++p)
      Rr[p] = *(const int4*)(A + (size_t)(bm + p*32 + r)*K + k0 + gc*8);
    #pragma unroll
    for (int p=0;p<NB;++p)
      Rr[NA+p] = *(const int4*)(B + (size_t)(bn + p*32 + r)*K + k0 + gc*8);
  };
  auto storeLds = [&](char* base, const int4* Rr) {
    #pragma unroll
    for (int p=0;p<NA;++p)
      *(int4*)(base + (p*32 + r)*128 + sl*16) = Rr[p];
    #pragma unroll
    for (int p=0;p<NB;++p)
      *(int4*)(base + ABYTES + (p*32 + r)*128 + sl*16) = Rr[NA+p];
  };
  auto compute = [&](const char* base) {
    const char* ab = base;
    const char* bb = base + ABYTES;
    #pragma unroll
    for (int step=0; step<2; ++step) {
      int c = step*4 + quad;
      short8 af[FM], bf[FN];
      #pragma unroll
      for (int m=0;m<FM;++m) {
        int Rw = wm + m*16 + lrow;
        af[m] = *(const short8*)(ab + Rw*128 + ((c ^ (Rw & 7))*16));
      }
      #pragma unroll
      for (int n=0;n<FN;++n) {
        int Rw = wn + n*16 + lrow;
        bf[n] = *(const short8*)(bb + Rw*128 + ((c ^ (Rw & 7))*16));
      }
      #pragma unroll
      for (int m=0;m<FM;++m)
        #pragma unroll
        for (int n=0;n<FN;++n)
          acc[m][n] = __builtin_amdgcn_mfma_f32_16x16x32_bf16(af[m], bf[n], acc[m][n], 0, 0, 0);
    }
  };

  load(0, Ra);
  load(1, Rb);
  for (int it = 0; it < nit; it += 2) {
    storeLds(lds, Ra);
    if (it + 2 < nit) load(it + 2, Ra);
    lds_barrier();
    compute(lds);
    storeLds(lds + TILE, Rb);
    if (it + 3 < nit) load(it + 3, Rb);
    lds_barrier();
    compute(lds + TILE);
  }

  #pragma unroll
  for (int m=0;m<FM;++m)
    #pragma unroll
    for (int n=0;n<FN;++n)
      #pragma unroll
      for (int rg=0;rg<4;++rg) {
        int row = bm + wm + m*16 + quad*4 + rg;
        int col = bn + wn + n*16 + lrow;
        float vv = acc[m][n][rg] + bqkv[col];
        int part = col >> 10, hh = (col >> 7) & 7, d = col & 127;
        unsigned short o = f2bu(vv);
        if (part == 0)      Qh[((size_t)hh*LL + row)*DKK + d] = o;
        else if (part == 1) Kh[((size_t)hh*LL + row)*DKK + d] = o;
        else                Vt[((size_t)hh*DKK + d)*LL + row] = o;
      }
}

// ---------------- qe + ql tables fused: one block per (i,h) ----------------
__global__ __launch_bounds__(64) void qtab_kernel(const unsigned short* __restrict__ Qh,
    const float* __restrict__ embk,
    const float* __restrict__ lqc, const float* __restrict__ lqt,
    const float* __restrict__ lcq, const float* __restrict__ ltq,
    float* __restrict__ qe, float* __restrict__ ql)
{
  int i = blockIdx.x, h = blockIdx.y, t = threadIdx.x;
  __shared__ float qrow[128];
  const unsigned short* qp = Qh + ((size_t)h*LL + i)*DKK;
  qrow[t] = b2f(qp[t]); qrow[t+64] = b2f(qp[t+64]);
  __syncthreads();
  if (t < RR) {
    float s = 0.f;
    #pragma unroll 8
    for (int d=0; d<128; ++d) s += qrow[d]*embk[t*128+d];
    qe[(i*HH+h)*RR + t] = s;
  } else if (t < RR + 12) {
    int u = t - RR;
    int tb = u/3, f = u - tb*3;
    const float* tab = (tb==0) ? lqc : (tb==1) ? lqt : (tb==2) ? lcq : ltq;
    const float* tr = tab + f*128;
    float s = 0.f;
    #pragma unroll 8
    for (int d=0; d<128; ++d) s += qrow[d]*tr[d];
    ql[((tb*LL + i)*HH + h)*3 + f] = s;
  }
}

// ---------------- bias + mask + softmax, in-place S -> P bf16 ----------------
__global__ __launch_bounds__(512) void softmax_kernel(
    float* __restrict__ S,
    const float* __restrict__ qe, const float* __restrict__ ql,
    const float* __restrict__ qcr, const float* __restrict__ cqr,
    const float* __restrict__ qtr, const float* __restrict__ tqr,
    const int* __restrict__ ct,   const int* __restrict__ pred,
    const int* __restrict__ mask)
{
  int i = blockIdx.x, h = blockIdx.y, j = threadIdx.x;
  __shared__ float qerow[52];
  __shared__ float red[512];
  if (j < RR) qerow[j] = qe[(i*HH+h)*RR + j];
  __syncthreads();

  float lq1[3] = {0,0,0}, lq2[3] = {0,0,0};
  if (i < QQ) {
    #pragma unroll
    for (int f=0; f<3; ++f) {
      lq1[f] = ql[((0*LL + i)*HH + h)*3 + f];
      lq2[f] = ql[((1*LL + i)*HH + h)*3 + f];
    }
  } else if (i < QQ+CCC) {
    #pragma unroll
    for (int f=0; f<3; ++f) lq1[f] = ql[((2*LL + i)*HH + h)*3 + f];
  } else {
    #pragma unroll
    for (int f=0; f<3; ++f) lq1[f] = ql[((3*LL + i)*HH + h)*3 + f];
  }

  float s = S[((size_t)h*LL + i)*LL + j];
  s += qerow[pred[i*LL + j]];
  if (i < QQ) {
    if (j < QQ) s += qerow[0];
    else if (j < QQ+CCC) { const float* r = qcr + (i*CCC + (j-QQ))*3;
      s += r[0]*lq1[0]+r[1]*lq1[1]+r[2]*lq1[2]; }
    else { const float* r = qtr + (i*TTT + (j-QQ-CCC))*3;
      s += r[0]*lq2[0]+r[1]*lq2[1]+r[2]*lq2[2]; }
  } else {
    if (j < QQ) {
      const float* r = (i < QQ+CCC) ? cqr + ((i-QQ)*QQ + j)*3
                                    : tqr + ((i-QQ-CCC)*QQ + j)*3;
      s += r[0]*lq1[0]+r[1]*lq1[1]+r[2]*lq1[2];
    } else {
      s += qerow[ct[(i-QQ)*(CCC+TTT) + (j-QQ)]];
    }
  }
  s *= 0.08838834764831845f;
  if (mask[i*LL + j] == 0) s = -1e9f;

  red[j] = s; __syncthreads();
  for (int st=256; st>0; st>>=1){ if (j<st) red[j]=fmaxf(red[j],red[j+st]); __syncthreads(); }
  float mx = red[0]; __syncthreads();
  float e = __expf(s - mx);
  red[j] = e; __syncthreads();
  for (int st=256; st>0; st>>=1){ if (j<st) red[j]+=red[j+st]; __syncthreads(); }
  float inv = 1.0f/red[0];
  ((unsigned short*)S)[((size_t)h*LL + i)*1024 + j] = f2bu(e*inv);
}

// ---------------- pw scatter + o2 = pw@embv + pf.tabs ----------------
__global__ __launch_bounds__(256) void pw_kernel(
    const unsigned short* __restrict__ P,   // ld 1024 shorts, [h][i] rows
    const float* __restrict__ embv,
    const float* __restrict__ lqc_v, const float* __restrict__ lcq_v,
    const float* __restrict__ lqt_v, const float* __restrict__ ltq_v,
    const float* __restrict__ qcr,  const float* __restrict__ cqr,
    const float* __restrict__ qtr,  const float* __restrict__ tqr,
    const int* __restrict__ ct,    const int* __restrict__ pred,
    float* __restrict__ o2)                 // [8][512][128]
{
  int i = blockIdx.x, t = threadIdx.x;
  __shared__ float pw8[8][56];
  __shared__ float pf1s[24], pf2s[24];
  __shared__ int predrow[512];
  __shared__ int ctrow[256];
  for (int k=t; k<8*56; k+=256) ((float*)pw8)[k] = 0.f;
  if (t < 24) { pf1s[t]=0.f; pf2s[t]=0.f; }
  for (int k=t; k<512; k+=256) predrow[k] = pred[i*LL + k];
  if (i >= QQ) { if (t < 256) ctrow[t] = ct[(i-QQ)*(CCC+TTT) + t]; }
  __syncthreads();

  int h = t >> 5, lane = t & 31;
  float qq = 0.f, l1[3] = {0,0,0}, l2[3] = {0,0,0};
  const unsigned short* Prow = P + ((size_t)h*LL + i)*1024;
  for (int jj = 0; jj < 16; ++jj) {
    int j = lane + jj*32;
    float p = b2f(Prow[j]);
    atomicAdd(&pw8[h][predrow[j]], p);
    if (i < QQ) {
      if (j < QQ) qq += p;
      else if (j < QQ+CCC) { const float* r = qcr + (i*CCC + (j-QQ))*3;
        l1[0]+=p*r[0]; l1[1]+=p*r[1]; l1[2]+=p*r[2]; }
      else { const float* r = qtr + (i*TTT + (j-QQ-CCC))*3;
        l2[0]+=p*r[0]; l2[1]+=p*r[1]; l2[2]+=p*r[2]; }
    } else {
      if (j < QQ) {
        const float* r = (i < QQ+CCC) ? cqr + ((i-QQ)*QQ + j)*3
                                      : tqr + ((i-QQ-CCC)*QQ + j)*3;
        l1[0]+=p*r[0]; l1[1]+=p*r[1]; l1[2]+=p*r[2];
      } else {
        atomicAdd(&pw8[h][ctrow[j-QQ]], p);
      }
    }
  }
  if (i < QQ) atomicAdd(&pw8[h][0], qq);
  atomicAdd(&pf1s[h*3+0], l1[0]); atomicAdd(&pf1s[h*3+1], l1[1]); atomicAdd(&pf1s[h*3+2], l1[2]);
  atomicAdd(&pf2s[h*3+0], l2[0]); atomicAdd(&pf2s[h*3+1], l2[1]); atomicAdd(&pf2s[h*3+2], l2[2]);
  __syncthreads();

  const float* tab1; const float* tab2 = nullptr;
  if (i < QQ)          { tab1 = lqc_v; tab2 = lqt_v; }
  else if (i < QQ+CCC) { tab1 = lcq_v; }
  else                 { tab1 = ltq_v; }

  for (int o = t; o < 1024; o += 256) {
    int h2 = o >> 7, d = o & 127;
    float acc = 0.f;
    #pragma unroll 5
    for (int r = 0; r < RR; ++r) acc += pw8[h2][r]*embv[r*128 + d];
    acc += pf1s[h2*3+0]*tab1[d] + pf1s[h2*3+1]*tab1[128+d] + pf1s[h2*3+2]*tab1[256+d];
    if (tab2) acc += pf2s[h2*3+0]*tab2[d] + pf2s[h2*3+1]*tab2[128+d] + pf2s[h2*3+2]*tab2[256+d];
    o2[((size_t)h2*LL + i)*DKK + d] = acc;
  }
}

// ---------------- launch ----------------
extern "C" void kernel_launch(void* const* d_in, const int* in_sizes, int n_in,
                              void* d_out, int out_size, void* d_ws, size_t ws_size,
                              hipStream_t stream)
{
  const float* x    = (const float*)d_in[0];
  const float* qcr  = (const float*)d_in[1];
  const float* cqr  = (const float*)d_in[2];
  const float* qtr  = (const float*)d_in[3];
  const float* tqr  = (const float*)d_in[4];
  const int*   ct   = (const int*)d_in[5];
  const int*   pred = (const int*)d_in[6];
  const int*   mask = (const int*)d_in[7];
  const float* embk = (const float*)d_in[8];
  const float* embv = (const float*)d_in[9];
  const float* lqc_k = (const float*)d_in[10];
  const float* lqc_v = (const float*)d_in[11];
  const float* lcq_k = (const float*)d_in[12];
  const float* lcq_v = (const float*)d_in[13];
  const float* lqt_k = (const float*)d_in[14];
  const float* lqt_v = (const float*)d_in[15];
  const float* ltq_k = (const float*)d_in[16];
  const float* ltq_v = (const float*)d_in[17];
  const float* Wq = (const float*)d_in[18]; const float* bq = (const float*)d_in[19];
  const float* Wk = (const float*)d_in[20]; const float* bk = (const float*)d_in[21];
  const float* Wv = (const float*)d_in[22]; const float* bv = (const float*)d_in[23];
  const float* Wo = (const float*)d_in[24]; const float* bo = (const float*)d_in[25];
  const float* ln1_g = (const float*)d_in[26]; const float* ln1_b = (const float*)d_in[27];
  const float* ln2_g = (const float*)d_in[28]; const float* ln2_b = (const float*)d_in[29];
  const float* W1 = (const float*)d_in[30]; const float* b1 = (const float*)d_in[31];
  const float* W2 = (const float*)d_in[32]; const float* b2 = (const float*)d_in[33];
  float* out = (float*)d_out;

  float* wsf = (float*)d_ws;
  float* S    = wsf;                       // [8][512][512] fp32; P bf16 in-place; later FFN hidden
  float* o2   = S + (size_t)HH*LL*LL;      // [8][512][128] fp32
  float* qe   = o2 + (size_t)HH*LL*DKK;    // [L,H,R]
  float* ql   = qe + LL*HH*RR;             // [4,L,H,3]
  float* bqkv = ql + 4*LL*HH*3;            // [3072]
  unsigned short* ub = (unsigned short*)(bqkv + 3072);
  unsigned short* ybuf_b = ub;                     // [L,D]
  unsigned short* obuf_b = ybuf_b + LL*DD;         // [L,D]
  unsigned short* Qh     = obuf_b + LL*DD;         // [H][L][DK]
  unsigned short* Kh     = Qh + LL*DD;             // [H][L][DK]
  unsigned short* Vt     = Kh + LL*DD;             // [H][DK][L]
  unsigned short* wqkv_b = Vt + LL*DD;             // [3072,1024]
  unsigned short* wo_b   = wqkv_b + (size_t)3*DD*DD;
  unsigned short* w1_b   = wo_b + (size_t)DD*DD;
  unsigned short* w2_b   = w1_b + (size_t)FFF*DD;
  unsigned short* PS     = (unsigned short*)S;     // P bf16, ld 1024 shorts
  unsigned short* hidden = (unsigned short*)S;     // [L][FFF] bf16 (after P dead)

  // 1. weights -> bf16
  conv_kernel<<<(3145728 + 768 + 255)/256, 256, 0, stream>>>(
      Wq, Wk, Wv, Wo, W1, W2, bq, bk, bv, wqkv_b, wo_b, w1_b, w2_b, bqkv);
  // 2. LN1 -> bf16
  ln_bf16_kernel<<<LL, 256, 0, stream>>>(x, ln1_g, ln1_b, ybuf_b);
  // 3. QKV GEMM (pipelined) with head scatter: 48x8 = 384 blocks
  gemm_qkv_pl<<<dim3(48, 8), 256, 0, stream>>>(ybuf_b, wqkv_b, bqkv, Qh, Kh, Vt);
  // 4. fused qe+ql tables
  qtab_kernel<<<dim3(LL, HH), 64, 0, stream>>>(Qh, embk, lqc_k, lqt_k, lcq_k, ltq_k, qe, ql);
  // 5. scores GEMM: S[h] = Qh[h] @ Kh[h]^T   (512 blocks)
  gemm_pl<64,64,0,0,0,0,0><<<dim3(8, 8, 8), 256, 0, stream>>>(
      Qh, DKK, (size_t)LL*DKK, Kh, DKK, (size_t)LL*DKK,
      nullptr, nullptr, 0, 0, S, LL, (size_t)LL*LL, DKK);
  // 6. bias+mask+softmax in-place -> P bf16
  softmax_kernel<<<dim3(LL, HH), 512, 0, stream>>>(S, qe, ql, qcr, cqr, qtr, tqr,
                                                   ct, pred, mask);
  // 7. pw scatter -> o2
  pw_kernel<<<LL, 256, 0, stream>>>(PS, embv, lqc_v, lcq_v, lqt_v, ltq_v,
                                    qcr, cqr, qtr, tqr, ct, pred, o2);
  // 8. PV GEMM + o2 add -> obuf bf16   (BN=32: 4x8x8 = 256 blocks)
  gemm_pl<64,32,0,1,0,1,0><<<dim3(4, 8, 8), 256, 0, stream>>>(
      PS, 1024, (size_t)LL*1024, Vt, LL, (size_t)DKK*LL,
      nullptr, o2, DKK, (size_t)LL*DKK, obuf_b, DD, (size_t)DKK, LL);
  // 9. out-proj + residual(x) -> out   (BN=32: 32x8 = 256 blocks)
  gemm_pl<64,32,0,0,0,1,1><<<dim3(32, 8, 1), 256, 0, stream>>>(
      obuf_b, DD, 0, wo_b, DD, 0, bo, x, DD, 0, out, DD, 0, DD);
  // 10. LN2 -> bf16 (reads h before bias-add!)
  ln_bf16_kernel<<<LL, 256, 0, stream>>>(out, ln2_g, ln2_b, ybuf_b);
  // 11. FFN1 relu -> hidden bf16  (64x8 = 512 blocks)
  gemm_pl<64,64,0,1,1,0,1><<<dim3(64, 8, 1), 256, 0, stream>>>(
      ybuf_b, DD, 0, w1_b, DD, 0, b1, nullptr, 0, 0, hidden, FFF, 0, DD);
  // 12. out += b2 (pre-init for split-K atomics)
  addbias_kernel<<<(LL*DD)/256, 256, 0, stream>>>(out, b2);
  // 13. FFN2 split-K x4, atomicAdd -> out   (16x8x4 = 512 blocks)
  gemm_pl<64,64,1,0,0,0,0><<<dim3(16, 8, 4), 256, 0, stream>>>(
      hidden, FFF, (size_t)1024, w2_b, FFF, (size_t)1024,
      nullptr, nullptr, 0, 0, out, DD, 0, 1024);
}

// Round 7
// 271.672 us; speedup vs baseline: 1.4290x; 1.4290x over previous
//
#include <hip/hip_runtime.h>
#include <hip/hip_bf16.h>

#define LL 512
#define DD 1024
#define HH 8
#define DKK 128
#define QQ 256
#define CCC 128
#define TTT 128
#define RR 50
#define FFF 4096

typedef __attribute__((ext_vector_type(8))) short short8;
typedef __attribute__((ext_vector_type(4))) float float4v;

__device__ __forceinline__ unsigned short f2bu(float f) {
  __hip_bfloat16 h = __float2bfloat16(f);
  unsigned short u; __builtin_memcpy(&u, &h, 2); return u;
}
__device__ __forceinline__ float b2f(unsigned short u) {
  unsigned int v = ((unsigned int)u) << 16;
  float f; __builtin_memcpy(&f, &v, 4); return f;
}

// barrier that only drains LDS (lgkmcnt(0)); global loads stay in flight.
// 0xC07F = vmcnt(63) expcnt(7) lgkmcnt(0) on gfx9-family encoding.
__device__ __forceinline__ void lds_barrier() {
  __builtin_amdgcn_sched_barrier(0);
  __builtin_amdgcn_s_waitcnt(0xC07F);
  __builtin_amdgcn_s_barrier();
  __builtin_amdgcn_sched_barrier(0);
}

// explicit-scalar load/store macros: NO arrays, NO pointer params -> no scratch
#define GLOADSET(R0,R1,S0,S1,itv) {                                          \
  int k0v = (itv) << 6;                                                      \
  R0 = *(const int4*)(Az + (size_t)(bm + r)*lda + k0v + gc*8);               \
  R1 = *(const int4*)(Az + (size_t)(bm + 32 + r)*lda + k0v + gc*8);          \
  S0 = *(const int4*)(Bz + (size_t)(bn + r)*ldb + k0v + gc*8);               \
  if constexpr (NB > 1) {                                                    \
    S1 = *(const int4*)(Bz + (size_t)(bn + 32 + r)*ldb + k0v + gc*8); } }

#define STORESET(basep,R0,R1,S0,S1) {                                        \
  char* bse = (basep);                                                       \
  *(int4*)(bse + r*128 + sl*16) = R0;                                        \
  *(int4*)(bse + (32 + r)*128 + sl*16) = R1;                                 \
  *(int4*)(bse + ABYTES + r*128 + sl*16) = S0;                               \
  if constexpr (NB > 1) {                                                    \
    *(int4*)(bse + ABYTES + (32 + r)*128 + sl*16) = S1; } }

// ---------------- weight fp32->bf16 conversion ----------------
__global__ __launch_bounds__(256) void conv_kernel(
    const float* __restrict__ Wq, const float* __restrict__ Wk,
    const float* __restrict__ Wv, const float* __restrict__ Wo,
    const float* __restrict__ W1, const float* __restrict__ W2,
    const float* __restrict__ bq, const float* __restrict__ bk,
    const float* __restrict__ bv,
    unsigned short* __restrict__ wqkv, unsigned short* __restrict__ wo,
    unsigned short* __restrict__ w1, unsigned short* __restrict__ w2,
    float* __restrict__ bqkv)
{
  int g = blockIdx.x * 256 + threadIdx.x;   // quad (4-float) index
  const float* src; unsigned short* dst; int off;
  if (g < 262144)        { src = Wq; dst = wqkv;           off = g; }
  else if (g < 524288)   { src = Wk; dst = wqkv + 1048576; off = g - 262144; }
  else if (g < 786432)   { src = Wv; dst = wqkv + 2097152; off = g - 524288; }
  else if (g < 1048576)  { src = Wo; dst = wo;             off = g - 786432; }
  else if (g < 2097152)  { src = W1; dst = w1;             off = g - 1048576; }
  else if (g < 3145728)  { src = W2; dst = w2;             off = g - 2097152; }
  else if (g < 3145728 + 768) {
    int q = g - 3145728;
    const float* s = (q < 256) ? bq : (q < 512) ? bk : bv;
    ((float4*)bqkv)[q] = ((const float4*)s)[q & 255];
    return;
  } else return;
  float4 v = ((const float4*)src)[off];
  ushort4 o4;
  o4.x = f2bu(v.x); o4.y = f2bu(v.y); o4.z = f2bu(v.z); o4.w = f2bu(v.w);
  ((ushort4*)dst)[off] = o4;
}

// ---------------- LayerNorm: fp32 in, bf16 out ----------------
__global__ __launch_bounds__(256) void ln_bf16_kernel(const float* __restrict__ x,
    const float* __restrict__ g, const float* __restrict__ b,
    unsigned short* __restrict__ y)
{
  int row = blockIdx.x, t = threadIdx.x;
  const float4 xv = ((const float4*)(x + row*DD))[t];
  float s  = xv.x+xv.y+xv.z+xv.w;
  float ss = xv.x*xv.x+xv.y*xv.y+xv.z*xv.z+xv.w*xv.w;
  __shared__ float rs[256], rss[256];
  rs[t]=s; rss[t]=ss; __syncthreads();
  for (int st=128; st>0; st>>=1){ if (t<st){ rs[t]+=rs[t+st]; rss[t]+=rss[t+st]; } __syncthreads(); }
  float mean = rs[0] * (1.0f/DD);
  float var  = rss[0]*(1.0f/DD) - mean*mean;
  float inv  = rsqrtf(var + 1e-5f);
  float4 gv = ((const float4*)g)[t], bv = ((const float4*)b)[t];
  ushort4 ov;
  ov.x = f2bu((xv.x-mean)*inv*gv.x + bv.x);
  ov.y = f2bu((xv.y-mean)*inv*gv.y + bv.y);
  ov.z = f2bu((xv.z-mean)*inv*gv.z + bv.z);
  ov.w = f2bu((xv.w-mean)*inv*gv.w + bv.w);
  ((ushort4*)(y + row*DD))[t] = ov;
}

// ---------------- tiny: out[row, col] += b2[col] ----------------
__global__ __launch_bounds__(256) void addbias_kernel(float* __restrict__ out,
                                                      const float* __restrict__ b2)
{
  int g = blockIdx.x*256 + threadIdx.x;   // over L*D
  out[g] += b2[g & (DD-1)];
}

// ======== VGPR-staged pipelined bf16 MFMA GEMM (explicit scalars) ========
// C[z][M,N] = A[z][M,K](lda) @ B[z][N,K](ldb)^T (+bias,+src,relu)
// 256 thr = 4 waves (2x2), BM=64 fixed, BN in {32,64}, BK=64, nit even.
// Register ping-pong sets are named scalars -> guaranteed VGPR residency.
template<int BN, int ZK, int OUT_BF16, int RELU, int HAS_SRC, int HAS_BIAS>
__global__ __launch_bounds__(256) void gemm_pl(
    const unsigned short* __restrict__ A, int lda, size_t sAz,
    const unsigned short* __restrict__ B, int ldb, size_t sBz,
    const float* __restrict__ bias,
    const float* __restrict__ src, int ldsrc, size_t sSz,
    void* __restrict__ Cv, int ldc, size_t sCz,
    int K)
{
  constexpr int BM = 64;
  constexpr int WM = 32, WN = BN/2, FM = 2, FN = WN/16;
  constexpr int NB = BN/32;
  constexpr int ABYTES = BM*128, TILE = ABYTES + BN*128;
  __shared__ char lds[2*TILE];
  int t = threadIdx.x, w = t >> 6, l = t & 63;
  size_t z = blockIdx.z;
  const unsigned short* Az = A + z*sAz;
  const unsigned short* Bz = B + z*sBz;
  int bm = blockIdx.y*BM, bn = blockIdx.x*BN;
  int wm = (w>>1)*WM, wn = (w&1)*WN;

  float4v acc[FM][FN];
  #pragma unroll
  for (int m=0;m<FM;++m)
    #pragma unroll
    for (int n=0;n<FN;++n) acc[m][n] = (float4v){0.f,0.f,0.f,0.f};

  int r = t >> 3, sl = t & 7;
  int gc = sl ^ (r & 7);
  int quad = l >> 4, lrow = l & 15;
  const int nit = K >> 6;           // even

  int4 a0, a1, b0, b1;              // ping set
  int4 c0, c1, d0, d1;              // pong set

  auto compute = [&](const char* base) {
    const char* ab = base;
    const char* bb = base + ABYTES;
    #pragma unroll
    for (int step=0; step<2; ++step) {
      int c = step*4 + quad;
      short8 af[FM], bf[FN];
      #pragma unroll
      for (int m=0;m<FM;++m) {
        int Rw = wm + m*16 + lrow;
        af[m] = *(const short8*)(ab + Rw*128 + ((c ^ (Rw & 7))*16));
      }
      #pragma unroll
      for (int n=0;n<FN;++n) {
        int Rw = wn + n*16 + lrow;
        bf[n] = *(const short8*)(bb + Rw*128 + ((c ^ (Rw & 7))*16));
      }
      #pragma unroll
      for (int m=0;m<FM;++m)
        #pragma unroll
        for (int n=0;n<FN;++n)
          acc[m][n] = __builtin_amdgcn_mfma_f32_16x16x32_bf16(af[m], bf[n], acc[m][n], 0, 0, 0);
    }
  };

  GLOADSET(a0,a1,b0,b1, 0);
  GLOADSET(c0,c1,d0,d1, 1);
  for (int it = 0; it < nit; it += 2) {
    STORESET(lds, a0,a1,b0,b1);                      // waits vmcnt for ping only
    if (it + 2 < nit) GLOADSET(a0,a1,b0,b1, it+2);   // prefetch stays in flight
    lds_barrier();
    compute(lds);
    STORESET(lds + TILE, c0,c1,d0,d1);
    if (it + 3 < nit) GLOADSET(c0,c1,d0,d1, it+3);
    lds_barrier();
    compute(lds + TILE);
  }

  #pragma unroll
  for (int m=0;m<FM;++m)
    #pragma unroll
    for (int n=0;n<FN;++n)
      #pragma unroll
      for (int rg=0;rg<4;++rg) {
        int row = bm + wm + m*16 + quad*4 + rg;
        int col = bn + wn + n*16 + lrow;
        float vv = acc[m][n][rg];
        if (ZK) {
          atomicAdd(&((float*)Cv)[(size_t)row*ldc + col], vv);
        } else {
          if (HAS_BIAS) vv += bias[col];
          if (HAS_SRC)  vv += src[z*sSz + (size_t)row*ldsrc + col];
          if (RELU) vv = fmaxf(vv, 0.f);
          if (OUT_BF16) ((unsigned short*)Cv)[z*sCz + (size_t)row*ldc + col] = f2bu(vv);
          else          ((float*)Cv)[z*sCz + (size_t)row*ldc + col] = vv;
        }
      }
}

// ---------------- QKV GEMM (same pipeline) + head-scatter epilogue ---------
__global__ __launch_bounds__(256) void gemm_qkv_pl(
    const unsigned short* __restrict__ A, const unsigned short* __restrict__ B,
    const float* __restrict__ bqkv,
    unsigned short* __restrict__ Qh, unsigned short* __restrict__ Kh,
    unsigned short* __restrict__ Vt)
{
  constexpr int BN = 64;
  constexpr int WM = 32, WN = 32, FM = 2, FN = 2;
  constexpr int NB = 2;
  constexpr int ABYTES = 64*128, TILE = ABYTES + BN*128;
  __shared__ char lds[2*TILE];
  int t = threadIdx.x, w = t >> 6, l = t & 63;
  int bm = blockIdx.y*64, bn = blockIdx.x*BN;
  int wm = (w>>1)*WM, wn = (w&1)*WN;
  const int lda = DD, ldb = DD, nit = DD >> 6;
  const unsigned short* Az = A;
  const unsigned short* Bz = B;

  float4v acc[FM][FN];
  #pragma unroll
  for (int m=0;m<FM;++m)
    #pragma unroll
    for (int n=0;n<FN;++n) acc[m][n] = (float4v){0.f,0.f,0.f,0.f};

  int r = t >> 3, sl = t & 7;
  int gc = sl ^ (r & 7);
  int quad = l >> 4, lrow = l & 15;

  int4 a0, a1, b0, b1;
  int4 c0, c1, d0, d1;

  auto compute = [&](const char* base) {
    const char* ab = base;
    const char* bb = base + ABYTES;
    #pragma unroll
    for (int step=0; step<2; ++step) {
      int c = step*4 + quad;
      short8 af[FM], bf[FN];
      #pragma unroll
      for (int m=0;m<FM;++m) {
        int Rw = wm + m*16 + lrow;
        af[m] = *(const short8*)(ab + Rw*128 + ((c ^ (Rw & 7))*16));
      }
      #pragma unroll
      for (int n=0;n<FN;++n) {
        int Rw = wn + n*16 + lrow;
        bf[n] = *(const short8*)(bb + Rw*128 + ((c ^ (Rw & 7))*16));
      }
      #pragma unroll
      for (int m=0;m<FM;++m)
        #pragma unroll
        for (int n=0;n<FN;++n)
          acc[m][n] = __builtin_amdgcn_mfma_f32_16x16x32_bf16(af[m], bf[n], acc[m][n], 0, 0, 0);
    }
  };

  GLOADSET(a0,a1,b0,b1, 0);
  GLOADSET(c0,c1,d0,d1, 1);
  for (int it = 0; it < nit; it += 2) {
    STORESET(lds, a0,a1,b0,b1);
    if (it + 2 < nit) GLOADSET(a0,a1,b0,b1, it+2);
    lds_barrier();
    compute(lds);
    STORESET(lds + TILE, c0,c1,d0,d1);
    if (it + 3 < nit) GLOADSET(c0,c1,d0,d1, it+3);
    lds_barrier();
    compute(lds + TILE);
  }

  #pragma unroll
  for (int m=0;m<FM;++m)
    #pragma unroll
    for (int n=0;n<FN;++n)
      #pragma unroll
      for (int rg=0;rg<4;++rg) {
        int row = bm + wm + m*16 + quad*4 + rg;
        int col = bn + wn + n*16 + lrow;
        float vv = acc[m][n][rg] + bqkv[col];
        int part = col >> 10, hh = (col >> 7) & 7, d = col & 127;
        unsigned short o = f2bu(vv);
        if (part == 0)      Qh[((size_t)hh*LL + row)*DKK + d] = o;
        else if (part == 1) Kh[((size_t)hh*LL + row)*DKK + d] = o;
        else                Vt[((size_t)hh*DKK + d)*LL + row] = o;
      }
}

// ---------------- qe + ql tables fused: one block per (i,h) ----------------
__global__ __launch_bounds__(64) void qtab_kernel(const unsigned short* __restrict__ Qh,
    const float* __restrict__ embk,
    const float* __restrict__ lqc, const float* __restrict__ lqt,
    const float* __restrict__ lcq, const float* __restrict__ ltq,
    float* __restrict__ qe, float* __restrict__ ql)
{
  int i = blockIdx.x, h = blockIdx.y, t = threadIdx.x;
  __shared__ float qrow[128];
  const unsigned short* qp = Qh + ((size_t)h*LL + i)*DKK;
  qrow[t] = b2f(qp[t]); qrow[t+64] = b2f(qp[t+64]);
  __syncthreads();
  if (t < RR) {
    float s = 0.f;
    #pragma unroll 8
    for (int d=0; d<128; ++d) s += qrow[d]*embk[t*128+d];
    qe[(i*HH+h)*RR + t] = s;
  } else if (t < RR + 12) {
    int u = t - RR;
    int tb = u/3, f = u - tb*3;
    const float* tab = (tb==0) ? lqc : (tb==1) ? lqt : (tb==2) ? lcq : ltq;
    const float* tr = tab + f*128;
    float s = 0.f;
    #pragma unroll 8
    for (int d=0; d<128; ++d) s += qrow[d]*tr[d];
    ql[((tb*LL + i)*HH + h)*3 + f] = s;
  }
}

// ---------------- bias + mask + softmax, in-place S -> P bf16 ----------------
__global__ __launch_bounds__(512) void softmax_kernel(
    float* __restrict__ S,
    const float* __restrict__ qe, const float* __restrict__ ql,
    const float* __restrict__ qcr, const float* __restrict__ cqr,
    const float* __restrict__ qtr, const float* __restrict__ tqr,
    const int* __restrict__ ct,   const int* __restrict__ pred,
    const int* __restrict__ mask)
{
  int i = blockIdx.x, h = blockIdx.y, j = threadIdx.x;
  __shared__ float qerow[52];
  __shared__ float red[512];
  if (j < RR) qerow[j] = qe[(i*HH+h)*RR + j];
  __syncthreads();

  float lq1[3] = {0,0,0}, lq2[3] = {0,0,0};
  if (i < QQ) {
    #pragma unroll
    for (int f=0; f<3; ++f) {
      lq1[f] = ql[((0*LL + i)*HH + h)*3 + f];
      lq2[f] = ql[((1*LL + i)*HH + h)*3 + f];
    }
  } else if (i < QQ+CCC) {
    #pragma unroll
    for (int f=0; f<3; ++f) lq1[f] = ql[((2*LL + i)*HH + h)*3 + f];
  } else {
    #pragma unroll
    for (int f=0; f<3; ++f) lq1[f] = ql[((3*LL + i)*HH + h)*3 + f];
  }

  float s = S[((size_t)h*LL + i)*LL + j];
  s += qerow[pred[i*LL + j]];
  if (i < QQ) {
    if (j < QQ) s += qerow[0];
    else if (j < QQ+CCC) { const float* r = qcr + (i*CCC + (j-QQ))*3;
      s += r[0]*lq1[0]+r[1]*lq1[1]+r[2]*lq1[2]; }
    else { const float* r = qtr + (i*TTT + (j-QQ-CCC))*3;
      s += r[0]*lq2[0]+r[1]*lq2[1]+r[2]*lq2[2]; }
  } else {
    if (j < QQ) {
      const float* r = (i < QQ+CCC) ? cqr + ((i-QQ)*QQ + j)*3
                                    : tqr + ((i-QQ-CCC)*QQ + j)*3;
      s += r[0]*lq1[0]+r[1]*lq1[1]+r[2]*lq1[2];
    } else {
      s += qerow[ct[(i-QQ)*(CCC+TTT) + (j-QQ)]];
    }
  }
  s *= 0.08838834764831845f;
  if (mask[i*LL + j] == 0) s = -1e9f;

  red[j] = s; __syncthreads();
  for (int st=256; st>0; st>>=1){ if (j<st) red[j]=fmaxf(red[j],red[j+st]); __syncthreads(); }
  float mx = red[0]; __syncthreads();
  float e = __expf(s - mx);
  red[j] = e; __syncthreads();
  for (int st=256; st>0; st>>=1){ if (j<st) red[j]+=red[j+st]; __syncthreads(); }
  float inv = 1.0f/red[0];
  ((unsigned short*)S)[((size_t)h*LL + i)*1024 + j] = f2bu(e*inv);
}

// ---------------- pw scatter + o2 = pw@embv + pf.tabs ----------------
__global__ __launch_bounds__(256) void pw_kernel(
    const unsigned short* __restrict__ P,   // ld 1024 shorts, [h][i] rows
    const float* __restrict__ embv,
    const float* __restrict__ lqc_v, const float* __restrict__ lcq_v,
    const float* __restrict__ lqt_v, const float* __restrict__ ltq_v,
    const float* __restrict__ qcr,  const float* __restrict__ cqr,
    const float* __restrict__ qtr,  const float* __restrict__ tqr,
    const int* __restrict__ ct,    const int* __restrict__ pred,
    float* __restrict__ o2)                 // [8][512][128]
{
  int i = blockIdx.x, t = threadIdx.x;
  __shared__ float pw8[8][56];
  __shared__ float pf1s[24], pf2s[24];
  __shared__ int predrow[512];
  __shared__ int ctrow[256];
  for (int k=t; k<8*56; k+=256) ((float*)pw8)[k] = 0.f;
  if (t < 24) { pf1s[t]=0.f; pf2s[t]=0.f; }
  for (int k=t; k<512; k+=256) predrow[k] = pred[i*LL + k];
  if (i >= QQ) { if (t < 256) ctrow[t] = ct[(i-QQ)*(CCC+TTT) + t]; }
  __syncthreads();

  int h = t >> 5, lane = t & 31;
  float qq = 0.f, l1[3] = {0,0,0}, l2[3] = {0,0,0};
  const unsigned short* Prow = P + ((size_t)h*LL + i)*1024;
  for (int jj = 0; jj < 16; ++jj) {
    int j = lane + jj*32;
    float p = b2f(Prow[j]);
    atomicAdd(&pw8[h][predrow[j]], p);
    if (i < QQ) {
      if (j < QQ) qq += p;
      else if (j < QQ+CCC) { const float* r = qcr + (i*CCC + (j-QQ))*3;
        l1[0]+=p*r[0]; l1[1]+=p*r[1]; l1[2]+=p*r[2]; }
      else { const float* r = qtr + (i*TTT + (j-QQ-CCC))*3;
        l2[0]+=p*r[0]; l2[1]+=p*r[1]; l2[2]+=p*r[2]; }
    } else {
      if (j < QQ) {
        const float* r = (i < QQ+CCC) ? cqr + ((i-QQ)*QQ + j)*3
                                      : tqr + ((i-QQ-CCC)*QQ + j)*3;
        l1[0]+=p*r[0]; l1[1]+=p*r[1]; l1[2]+=p*r[2];
      } else {
        atomicAdd(&pw8[h][ctrow[j-QQ]], p);
      }
    }
  }
  if (i < QQ) atomicAdd(&pw8[h][0], qq);
  atomicAdd(&pf1s[h*3+0], l1[0]); atomicAdd(&pf1s[h*3+1], l1[1]); atomicAdd(&pf1s[h*3+2], l1[2]);
  atomicAdd(&pf2s[h*3+0], l2[0]); atomicAdd(&pf2s[h*3+1], l2[1]); atomicAdd(&pf2s[h*3+2], l2[2]);
  __syncthreads();

  const float* tab1; const float* tab2 = nullptr;
  if (i < QQ)          { tab1 = lqc_v; tab2 = lqt_v; }
  else if (i < QQ+CCC) { tab1 = lcq_v; }
  else                 { tab1 = ltq_v; }

  for (int o = t; o < 1024; o += 256) {
    int h2 = o >> 7, d = o & 127;
    float acc = 0.f;
    #pragma unroll 5
    for (int r = 0; r < RR; ++r) acc += pw8[h2][r]*embv[r*128 + d];
    acc += pf1s[h2*3+0]*tab1[d] + pf1s[h2*3+1]*tab1[128+d] + pf1s[h2*3+2]*tab1[256+d];
    if (tab2) acc += pf2s[h2*3+0]*tab2[d] + pf2s[h2*3+1]*tab2[128+d] + pf2s[h2*3+2]*tab2[256+d];
    o2[((size_t)h2*LL + i)*DKK + d] = acc;
  }
}

// ---------------- launch ----------------
extern "C" void kernel_launch(void* const* d_in, const int* in_sizes, int n_in,
                              void* d_out, int out_size, void* d_ws, size_t ws_size,
                              hipStream_t stream)
{
  const float* x    = (const float*)d_in[0];
  const float* qcr  = (const float*)d_in[1];
  const float* cqr  = (const float*)d_in[2];
  const float* qtr  = (const float*)d_in[3];
  const float* tqr  = (const float*)d_in[4];
  const int*   ct   = (const int*)d_in[5];
  const int*   pred = (const int*)d_in[6];
  const int*   mask = (const int*)d_in[7];
  const float* embk = (const float*)d_in[8];
  const float* embv = (const float*)d_in[9];
  const float* lqc_k = (const float*)d_in[10];
  const float* lqc_v = (const float*)d_in[11];
  const float* lcq_k = (const float*)d_in[12];
  const float* lcq_v = (const float*)d_in[13];
  const float* lqt_k = (const float*)d_in[14];
  const float* lqt_v = (const float*)d_in[15];
  const float* ltq_k = (const float*)d_in[16];
  const float* ltq_v = (const float*)d_in[17];
  const float* Wq = (const float*)d_in[18]; const float* bq = (const float*)d_in[19];
  const float* Wk = (const float*)d_in[20]; const float* bk = (const float*)d_in[21];
  const float* Wv = (const float*)d_in[22]; const float* bv = (const float*)d_in[23];
  const float* Wo = (const float*)d_in[24]; const float* bo = (const float*)d_in[25];
  const float* ln1_g = (const float*)d_in[26]; const float* ln1_b = (const float*)d_in[27];
  const float* ln2_g = (const float*)d_in[28]; const float* ln2_b = (const float*)d_in[29];
  const float* W1 = (const float*)d_in[30]; const float* b1 = (const float*)d_in[31];
  const float* W2 = (const float*)d_in[32]; const float* b2 = (const float*)d_in[33];
  float* out = (float*)d_out;

  float* wsf = (float*)d_ws;
  float* S    = wsf;                       // [8][512][512] fp32; P bf16 in-place; later FFN hidden
  float* o2   = S + (size_t)HH*LL*LL;      // [8][512][128] fp32
  float* qe   = o2 + (size_t)HH*LL*DKK;    // [L,H,R]
  float* ql   = qe + LL*HH*RR;             // [4,L,H,3]
  float* bqkv = ql + 4*LL*HH*3;            // [3072]
  unsigned short* ub = (unsigned short*)(bqkv + 3072);
  unsigned short* ybuf_b = ub;                     // [L,D]
  unsigned short* obuf_b = ybuf_b + LL*DD;         // [L,D]
  unsigned short* Qh     = obuf_b + LL*DD;         // [H][L][DK]
  unsigned short* Kh     = Qh + LL*DD;             // [H][L][DK]
  unsigned short* Vt     = Kh + LL*DD;             // [H][DK][L]
  unsigned short* wqkv_b = Vt + LL*DD;             // [3072,1024]
  unsigned short* wo_b   = wqkv_b + (size_t)3*DD*DD;
  unsigned short* w1_b   = wo_b + (size_t)DD*DD;
  unsigned short* w2_b   = w1_b + (size_t)FFF*DD;
  unsigned short* PS     = (unsigned short*)S;     // P bf16, ld 1024 shorts
  unsigned short* hidden = (unsigned short*)S;     // [L][FFF] bf16 (after P dead)

  // 1. weights -> bf16
  conv_kernel<<<(3145728 + 768 + 255)/256, 256, 0, stream>>>(
      Wq, Wk, Wv, Wo, W1, W2, bq, bk, bv, wqkv_b, wo_b, w1_b, w2_b, bqkv);
  // 2. LN1 -> bf16
  ln_bf16_kernel<<<LL, 256, 0, stream>>>(x, ln1_g, ln1_b, ybuf_b);
  // 3. QKV GEMM (pipelined) with head scatter: 48x8 = 384 blocks
  gemm_qkv_pl<<<dim3(48, 8), 256, 0, stream>>>(ybuf_b, wqkv_b, bqkv, Qh, Kh, Vt);
  // 4. fused qe+ql tables
  qtab_kernel<<<dim3(LL, HH), 64, 0, stream>>>(Qh, embk, lqc_k, lqt_k, lcq_k, ltq_k, qe, ql);
  // 5. scores GEMM: S[h] = Qh[h] @ Kh[h]^T   (512 blocks)
  gemm_pl<64,0,0,0,0,0><<<dim3(8, 8, 8), 256, 0, stream>>>(
      Qh, DKK, (size_t)LL*DKK, Kh, DKK, (size_t)LL*DKK,
      nullptr, nullptr, 0, 0, S, LL, (size_t)LL*LL, DKK);
  // 6. bias+mask+softmax in-place -> P bf16
  softmax_kernel<<<dim3(LL, HH), 512, 0, stream>>>(S, qe, ql, qcr, cqr, qtr, tqr,
                                                   ct, pred, mask);
  // 7. pw scatter -> o2
  pw_kernel<<<LL, 256, 0, stream>>>(PS, embv, lqc_v, lcq_v, lqt_v, ltq_v,
                                    qcr, cqr, qtr, tqr, ct, pred, o2);
  // 8. PV GEMM + o2 add -> obuf bf16   (BN=32: 4x8x8 = 256 blocks)
  gemm_pl<32,0,1,0,1,0><<<dim3(4, 8, 8), 256, 0, stream>>>(
      PS, 1024, (size_t)LL*1024, Vt, LL, (size_t)DKK*LL,
      nullptr, o2, DKK, (size_t)LL*DKK, obuf_b, DD, (size_t)DKK, LL);
  // 9. out-proj + residual(x) -> out   (BN=32: 32x8 = 256 blocks)
  gemm_pl<32,0,0,0,1,1><<<dim3(32, 8, 1), 256, 0, stream>>>(
      obuf_b, DD, 0, wo_b, DD, 0, bo, x, DD, 0, out, DD, 0, DD);
  // 10. LN2 -> bf16 (reads h before bias-add!)
  ln_bf16_kernel<<<LL, 256, 0, stream>>>(out, ln2_g, ln2_b, ybuf_b);
  // 11. FFN1 relu -> hidden bf16  (64x8 = 512 blocks)
  gemm_pl<64,0,1,1,0,1><<<dim3(64, 8, 1), 256, 0, stream>>>(
      ybuf_b, DD, 0, w1_b, DD, 0, b1, nullptr, 0, 0, hidden, FFF, 0, DD);
  // 12. out += b2 (pre-init for split-K atomics)
  addbias_kernel<<<(LL*DD)/256, 256, 0, stream>>>(out, b2);
  // 13. FFN2 split-K x4, atomicAdd -> out   (16x8x4 = 512 blocks)
  gemm_pl<64,1,0,0,0,0><<<dim3(16, 8, 4), 256, 0, stream>>>(
      hidden, FFF, (size_t)1024, w2_b, FFF, (size_t)1024,
      nullptr, nullptr, 0, 0, out, DD, 0, 1024);
}